// Round 8
// baseline (175.339 us; speedup 1.0000x reference)
//
#include <hip/hip_runtime.h>

#define B_ 8
#define L_ 1024
#define D_ 768
#define E_ 4
#define H_ 1536

typedef __attribute__((ext_vector_type(8))) short bf16x8;
typedef __attribute__((ext_vector_type(4))) float f32x4;

#define AS1 __attribute__((address_space(1)))
#define AS3 __attribute__((address_space(3)))

__device__ __forceinline__ unsigned short f2bf(float f) {
  unsigned int u = __float_as_uint(f);
  u += 0x7FFFu + ((u >> 16) & 1u);
  return (unsigned short)(u >> 16);
}
__device__ __forceinline__ float bf2f(unsigned short h) {
  return __uint_as_float(((unsigned int)h) << 16);
}

// ---- branch-free fast activations (hw exp2/rcp) ----
__device__ __forceinline__ float sigm(float z) {            // 1/(1+e^-z)
  return __builtin_amdgcn_rcpf(1.0f + __builtin_amdgcn_exp2f(z * -1.442695040888963f));
}
__device__ __forceinline__ float act_fn(float v, int e) {
  if (e == 1) return v * sigm(v);                           // silu
  if (e == 2) {                                             // mish = v*tanh(softplus(v))
    float p = __builtin_amdgcn_exp2f(fminf(v, 30.0f) * 1.442695040888963f);
    float q = 1.0f + p, q2 = q * q;                         // tanh(ln q) = (q^2-1)/(q^2+1)
    return v * (q2 - 1.0f) * __builtin_amdgcn_rcpf(q2 + 1.0f);
  }
  float u = v * (0.7978845608028654f + 0.0356774081f * v * v);  // gelu = v*sigma(2u)
  return v * sigm(2.0f * u);
}

// ---------- K0: convert x -> bf16 + partial column sums (vectorized, block=192) ----------
__global__ __launch_bounds__(192) void k_cvtx_pool(const float* __restrict__ x,
                                                   unsigned short* __restrict__ xbf,
                                                   float* __restrict__ part) {
  const int c = blockIdx.x;
  const int b = blockIdx.y;
  const int t = threadIdx.x;
  const float* xb = x + ((size_t)b * L_ + (size_t)c * 64) * D_;
  unsigned short* ob = xbf ? xbf + ((size_t)b * L_ + (size_t)c * 64) * D_ : nullptr;
  float4 s = make_float4(0.f, 0.f, 0.f, 0.f);
  for (int l = 0; l < 64; ++l) {
    float4 v = *(const float4*)(xb + (size_t)l * D_ + t * 4);
    s.x += v.x; s.y += v.y; s.z += v.z; s.w += v.w;
    if (ob)
      *(ushort4*)(ob + (size_t)l * D_ + t * 4) =
          make_ushort4(f2bf(v.x), f2bf(v.y), f2bf(v.z), f2bf(v.w));
  }
  *(float4*)(part + ((size_t)b * 16 + c) * D_ + t * 4) = s;
}

// ---------- K1: routing ----------
__global__ __launch_bounds__(256) void k_route(const float* __restrict__ part,
                                               const float* __restrict__ rw,
                                               const float* __restrict__ rb,
                                               int* __restrict__ slot_e,
                                               float* __restrict__ slot_g) {
  const int b = blockIdx.x;
  const int t = threadIdx.x;
  __shared__ float red[256][4];
  float p0 = 0.f, p1 = 0.f, p2 = 0.f;
  const float* pb = part + (size_t)b * 16 * D_;
  for (int c = 0; c < 16; ++c) {
    p0 += pb[c * D_ + t];
    p1 += pb[c * D_ + t + 256];
    p2 += pb[c * D_ + t + 512];
  }
  p0 *= (1.0f / L_); p1 *= (1.0f / L_); p2 *= (1.0f / L_);
  for (int e = 0; e < 4; ++e)
    red[t][e] = p0 * rw[e * D_ + t] + p1 * rw[e * D_ + t + 256] + p2 * rw[e * D_ + t + 512];
  __syncthreads();
  for (int s = 128; s > 0; s >>= 1) {
    if (t < s)
      for (int e = 0; e < 4; ++e) red[t][e] += red[t + s][e];
    __syncthreads();
  }
  if (t == 0) {
    float lg[4];
    for (int e = 0; e < 4; ++e) lg[e] = red[0][e] + rb[e];
    int i0 = 0;
    for (int e = 1; e < 4; ++e) if (lg[e] > lg[i0]) i0 = e;
    int i1 = -1;
    for (int e = 0; e < 4; ++e) {
      if (e == i0) continue;
      if (i1 < 0 || lg[e] > lg[i1]) i1 = e;
    }
    float ex = expf(lg[i1] - lg[i0]);
    slot_e[2 * b]     = i0; slot_g[2 * b]     = 1.0f / (1.0f + ex);
    slot_e[2 * b + 1] = i1; slot_g[2 * b + 1] = ex / (1.0f + ex);
  }
}

// ---------- K2: transpose+convert weights: f32 [E][R][C] -> bf16 [E][C][R] ----------
__global__ __launch_bounds__(256) void k_cvtw(const float* __restrict__ src,
                                              unsigned short* __restrict__ dst,
                                              int R, int C) {
  __shared__ float tile[32][33];
  const int e = blockIdx.z;
  const float* s = src + (size_t)e * R * C;
  unsigned short* d = dst + (size_t)e * R * C;
  const int c0 = blockIdx.x * 32, r0 = blockIdx.y * 32;
  const int tx = threadIdx.x & 31, ty = threadIdx.x >> 5;
#pragma unroll
  for (int i = 0; i < 32; i += 8)
    tile[ty + i][tx] = s[(size_t)(r0 + ty + i) * C + c0 + tx];
  __syncthreads();
  const int c = threadIdx.x >> 3, r4 = (threadIdx.x & 7) * 4;
  ushort4 o = make_ushort4(f2bf(tile[r4 + 0][c]), f2bf(tile[r4 + 1][c]),
                           f2bf(tile[r4 + 2][c]), f2bf(tile[r4 + 3][c]));
  *(ushort4*)&d[(size_t)(c0 + c) * R + r0 + r4] = o;
}

// ---------- swizzled global_load_lds staging of a 128x32 bf16 subtile (8 KB) ----------
// bank-group (4*row + slot) % 8 is a permutation over rows 0..7 -> 2-way aliasing (free).
// Both-sides swizzle: linear LDS dest, pre-swizzled global source, swizzled read.
__device__ __forceinline__ void stage_tile(const unsigned short* __restrict__ src, int pitch,
                                           unsigned short* lds, int t) {
#pragma unroll
  for (int rnd = 0; rnd < 2; ++rnd) {
    const int o = rnd * 4096 + t * 16;                     // dest byte offset
    const int row = o >> 6;
    const int kb = (o & 63) ^ (((row >> 1) & 3) << 4);     // swizzled source byte-in-row
    const unsigned short* g = src + (size_t)row * pitch + (kb >> 1);
    unsigned short* d = lds + ((o & ~1023) >> 1);          // wave-uniform base
    __builtin_amdgcn_global_load_lds((AS1 const void*)g, (AS3 void*)d, 16, 0, 0);
  }
}

// stage a 128x64 tile as two 128x32 k-half subtiles (16 KB): 4 loads/thread
__device__ __forceinline__ void stage64(const unsigned short* __restrict__ src, int pitch,
                                        unsigned short* lds, int t) {
  stage_tile(src,      pitch, lds,        t);
  stage_tile(src + 32, pitch, lds + 4096, t);
}

__device__ __forceinline__ bf16x8 frag(const unsigned short* lds, int row, int kq8) {
  const int byte = (row << 6) + ((kq8 << 1) ^ (((row >> 1) & 3) << 4));
  return *(const bf16x8*)((const char*)lds + byte);
}

__device__ __forceinline__ void block_bar() {
  asm volatile("" ::: "memory");
  __builtin_amdgcn_s_barrier();
  asm volatile("" ::: "memory");
}

// ---------- K3a: GEMM1, BK=64 depth-2 ring + counted vmcnt; LDS-bounce epilogue ----------
__global__ __launch_bounds__(256) void k_ffn1a(const unsigned short* __restrict__ xbf,
                                               const unsigned short* __restrict__ w1t,
                                               const float* __restrict__ b1,
                                               const int* __restrict__ slot_e,
                                               const float* __restrict__ slot_g,
                                               unsigned short* __restrict__ hact) {
  __shared__ char smem[65536];   // A slots @0,16384; B slots @32768,49152 (16 KB each)
  // chunked XCD swizzle: 1536 blocks, 192/XCD
  int wg = blockIdx.x;
  wg = (wg & 7) * 192 + (wg >> 3);
  const int hx = wg % 12;
  const int ly = (wg / 12) & 7;
  const int s  = wg / 96;
  const int e = slot_e[s];
  const float g = slot_g[s];
  const int b = s >> 1;
  const int l0 = ly * 128, h0 = hx * 128;
  const int t = threadIdx.x, lane = t & 63, w = t >> 6;
  const int wm = (w >> 1) * 64, wn = (w & 1) * 64;
  const int c16 = lane & 15, kq8 = (lane >> 4) * 8, rq = (lane >> 4) * 4;
  const unsigned short* A  = xbf + ((size_t)b * L_ + l0) * D_;
  const unsigned short* Bp = w1t + ((size_t)e * H_ + h0) * D_;
  f32x4 acc[4][4] = {};
  const int NT = D_ / 64;   // 12

  stage64(A,      D_, (unsigned short*)(smem),         t);
  stage64(Bp,     D_, (unsigned short*)(smem + 32768), t);
  stage64(A + 64, D_, (unsigned short*)(smem + 16384), t);
  stage64(Bp + 64, D_, (unsigned short*)(smem + 49152), t);
  int cb = 0;
  for (int kt = 0; kt < NT; ++kt) {
    if (kt < NT - 1) asm volatile("s_waitcnt vmcnt(8)" ::: "memory");
    else             asm volatile("s_waitcnt vmcnt(0)" ::: "memory");
    block_bar();                              // tile kt visible to all waves
#pragma unroll
    for (int kh = 0; kh < 2; ++kh) {
      const unsigned short* Ac = (const unsigned short*)(smem + cb * 16384 + kh * 8192);
      const unsigned short* Bc = (const unsigned short*)(smem + 32768 + cb * 16384 + kh * 8192);
      bf16x8 af[4], bfr[4];
#pragma unroll
      for (int i = 0; i < 4; ++i) af[i]  = frag(Ac, wm + i * 16 + c16, kq8);
#pragma unroll
      for (int i = 0; i < 4; ++i) bfr[i] = frag(Bc, wn + i * 16 + c16, kq8);
#pragma unroll
      for (int mi = 0; mi < 4; ++mi)
#pragma unroll
        for (int ni = 0; ni < 4; ++ni)
          acc[mi][ni] = __builtin_amdgcn_mfma_f32_16x16x32_bf16(af[mi], bfr[ni], acc[mi][ni], 0, 0, 0);
    }
    block_bar();                              // all waves done reading buf[cb]
    if (kt + 2 < NT) {
      stage64(A + (kt + 2) * 64,  D_, (unsigned short*)(smem + cb * 16384), t);
      stage64(Bp + (kt + 2) * 64, D_, (unsigned short*)(smem + 32768 + cb * 16384), t);
    }
    cb ^= 1;
  }

  // epilogue: act -> bf16 -> LDS tile [128][136] -> 16B coalesced stores (256B runs)
  const float* b1e = b1 + (size_t)e * H_;
  unsigned short* Cl = (unsigned short*)smem;
#pragma unroll
  for (int ni = 0; ni < 4; ++ni) {
    int n = wn + ni * 16 + c16;
    float bias = b1e[h0 + n];
#pragma unroll
    for (int mi = 0; mi < 4; ++mi)
#pragma unroll
      for (int j = 0; j < 4; ++j) {
        int m = wm + mi * 16 + rq + j;
        Cl[m * 136 + n] = f2bf(act_fn(acc[mi][ni][j] + bias, e) * g);
      }
  }
  __syncthreads();
  unsigned short* hs = hact + (((size_t)s * L_ + l0) * H_) + h0;
  const int rr = t >> 4, cc8 = (t & 15) * 8;
#pragma unroll
  for (int i = 0; i < 8; ++i) {
    int r = i * 16 + rr;
    *(bf16x8*)(hs + (size_t)r * H_ + cc8) = *(const bf16x8*)(Cl + r * 136 + cc8);
  }
}

// ---------- K4a: GEMM2, BK=64 depth-2 ring; si=0 -> y f32(+resid), si=1 -> ypart ----------
__global__ __launch_bounds__(256) void k_ffn2a(const unsigned short* __restrict__ hact,
                                               const unsigned short* __restrict__ w2t,
                                               const float* __restrict__ b2,
                                               const int* __restrict__ slot_e,
                                               const float* __restrict__ slot_g,
                                               const float* __restrict__ x,
                                               float* __restrict__ y,
                                               unsigned short* __restrict__ ypart) {
  __shared__ char smem[65536];
  // chunked XCD swizzle: 768 blocks, 96/XCD
  int wg = blockIdx.x;
  wg = (wg & 7) * 96 + (wg >> 3);
  const int dx = wg % 6;
  const int ly = (wg / 6) & 7;
  const int s  = wg / 48;
  const int si = s & 1, b = s >> 1;
  const int e = slot_e[s];
  const float g = slot_g[s];
  const int l0 = ly * 128, d0 = dx * 128;
  const int t = threadIdx.x, lane = t & 63, w = t >> 6;
  const int wm = (w >> 1) * 64, wn = (w & 1) * 64;
  const int c16 = lane & 15, kq8 = (lane >> 4) * 8, rq = (lane >> 4) * 4;
  const unsigned short* A  = hact + ((size_t)s * L_ + l0) * H_;
  const unsigned short* Bp = w2t + ((size_t)e * D_ + d0) * H_;
  f32x4 acc[4][4] = {};
  const int NT = H_ / 64;   // 24

  stage64(A,      H_, (unsigned short*)(smem),         t);
  stage64(Bp,     H_, (unsigned short*)(smem + 32768), t);
  stage64(A + 64, H_, (unsigned short*)(smem + 16384), t);
  stage64(Bp + 64, H_, (unsigned short*)(smem + 49152), t);
  int cb = 0;
  for (int kt = 0; kt < NT; ++kt) {
    if (kt < NT - 1) asm volatile("s_waitcnt vmcnt(8)" ::: "memory");
    else             asm volatile("s_waitcnt vmcnt(0)" ::: "memory");
    block_bar();
#pragma unroll
    for (int kh = 0; kh < 2; ++kh) {
      const unsigned short* Ac = (const unsigned short*)(smem + cb * 16384 + kh * 8192);
      const unsigned short* Bc = (const unsigned short*)(smem + 32768 + cb * 16384 + kh * 8192);
      bf16x8 af[4], bfr[4];
#pragma unroll
      for (int i = 0; i < 4; ++i) af[i]  = frag(Ac, wm + i * 16 + c16, kq8);
#pragma unroll
      for (int i = 0; i < 4; ++i) bfr[i] = frag(Bc, wn + i * 16 + c16, kq8);
#pragma unroll
      for (int mi = 0; mi < 4; ++mi)
#pragma unroll
        for (int ni = 0; ni < 4; ++ni)
          acc[mi][ni] = __builtin_amdgcn_mfma_f32_16x16x32_bf16(af[mi], bfr[ni], acc[mi][ni], 0, 0, 0);
    }
    block_bar();
    if (kt + 2 < NT) {
      stage64(A + (kt + 2) * 64,  H_, (unsigned short*)(smem + cb * 16384), t);
      stage64(Bp + (kt + 2) * 64, H_, (unsigned short*)(smem + 32768 + cb * 16384), t);
    }
    cb ^= 1;
  }

  if (si == 0) {
    const float* xb = x + (size_t)b * L_ * D_;
    float* yb = y + (size_t)b * L_ * D_;
#pragma unroll
    for (int ni = 0; ni < 4; ++ni) {
      int n = d0 + wn + ni * 16 + c16;
      float bias = g * b2[(size_t)e * D_ + n];
#pragma unroll
      for (int mi = 0; mi < 4; ++mi)
#pragma unroll
        for (int j = 0; j < 4; ++j) {
          int m = l0 + wm + mi * 16 + rq + j;
          yb[(size_t)m * D_ + n] = acc[mi][ni][j] + bias + xb[(size_t)m * D_ + n];
        }
    }
  } else {
    unsigned short* Cl = (unsigned short*)smem;
#pragma unroll
    for (int ni = 0; ni < 4; ++ni) {
      int n = wn + ni * 16 + c16;
      float bias = g * b2[(size_t)e * D_ + d0 + n];
#pragma unroll
      for (int mi = 0; mi < 4; ++mi)
#pragma unroll
        for (int j = 0; j < 4; ++j) {
          int m = wm + mi * 16 + rq + j;
          Cl[m * 136 + n] = f2bf(acc[mi][ni][j] + bias);
        }
    }
    __syncthreads();
    unsigned short* yp = ypart + ((size_t)b * L_ + l0) * D_ + d0;
    const int rr = t >> 4, cc8 = (t & 15) * 8;
#pragma unroll
    for (int i = 0; i < 8; ++i) {
      int r = i * 16 + rr;
      *(bf16x8*)(yp + (size_t)r * D_ + cc8) = *(const bf16x8*)(Cl + r * 136 + cc8);
    }
  }
}

// ---------- K5: row LayerNorm, 1 wave per row, shuffle reductions, no LDS ----------
__global__ __launch_bounds__(256) void k_ln(float* __restrict__ y,
                                            const unsigned short* __restrict__ yp,
                                            const float* __restrict__ g,
                                            const float* __restrict__ bt) {
  const int t = threadIdx.x;
  const int row = blockIdx.x * 4 + (t >> 6);
  const int lane = t & 63;
  float* yr = y + (size_t)row * D_;
  float4 v[3];
  float sum = 0.f;
#pragma unroll
  for (int i = 0; i < 3; ++i) {
    v[i] = *(const float4*)(yr + i * 256 + lane * 4);
    if (yp) {
      ushort4 p = *(const ushort4*)(yp + (size_t)row * D_ + i * 256 + lane * 4);
      v[i].x += bf2f(p.x); v[i].y += bf2f(p.y); v[i].z += bf2f(p.z); v[i].w += bf2f(p.w);
    }
    sum += v[i].x + v[i].y + v[i].z + v[i].w;
  }
#pragma unroll
  for (int off = 32; off > 0; off >>= 1) sum += __shfl_xor(sum, off);
  const float mu = sum * (1.0f / D_);
  float var = 0.f;
#pragma unroll
  for (int i = 0; i < 3; ++i) {
    v[i].x -= mu; v[i].y -= mu; v[i].z -= mu; v[i].w -= mu;
    var += v[i].x * v[i].x + v[i].y * v[i].y + v[i].z * v[i].z + v[i].w * v[i].w;
  }
#pragma unroll
  for (int off = 32; off > 0; off >>= 1) var += __shfl_xor(var, off);
  const float rstd = rsqrtf(var * (1.0f / D_) + 1e-5f);
#pragma unroll
  for (int i = 0; i < 3; ++i) {
    float4 gg = *(const float4*)(g + i * 256 + lane * 4);
    float4 bb = *(const float4*)(bt + i * 256 + lane * 4);
    float4 o;
    o.x = v[i].x * rstd * gg.x + bb.x;
    o.y = v[i].y * rstd * gg.y + bb.y;
    o.z = v[i].z * rstd * gg.z + bb.z;
    o.w = v[i].w * rstd * gg.w + bb.w;
    *(float4*)(yr + i * 256 + lane * 4) = o;
  }
}

// ================= fallback (mode B, round-1 proven kernels) =================
__global__ __launch_bounds__(256) void k_ffn1b(const float* __restrict__ x,
                                               const float* __restrict__ w1,
                                               const float* __restrict__ b1,
                                               const int* __restrict__ slot_e,
                                               const float* __restrict__ slot_g,
                                               unsigned short* __restrict__ hact) {
  __shared__ unsigned short Al[128][40];
  __shared__ unsigned short Bl[128][40];
  const int s = blockIdx.z;
  const int e = slot_e[s];
  const float g = slot_g[s];
  const int b = s >> 1;
  const int l0 = blockIdx.y * 128, h0 = blockIdx.x * 128;
  const int t = threadIdx.x, lane = t & 63, w = t >> 6;
  const int wm = (w >> 1) * 64, wn = (w & 1) * 64;
  const int c16 = lane & 15, kq = (lane >> 4) * 8, rq = (lane >> 4) * 4;
  const int ar = t >> 3, ac = (t & 7) * 4;
  const int bn = t & 127, bk0 = (t >> 7) * 4;
  const float* xb  = x  + (size_t)b * L_ * D_;
  const float* w1e = w1 + (size_t)e * D_ * H_;
  f32x4 acc[4][4] = {};
  for (int k0 = 0; k0 < D_; k0 += 32) {
#pragma unroll
    for (int p = 0; p < 4; ++p) {
      int r = p * 32 + ar;
      float4 v = *(const float4*)(xb + (size_t)(l0 + r) * D_ + (k0 + ac));
      *(ushort4*)&Al[r][ac] = make_ushort4(f2bf(v.x), f2bf(v.y), f2bf(v.z), f2bf(v.w));
    }
#pragma unroll
    for (int p = 0; p < 4; ++p) {
      int kk = bk0 + p * 8;
      const float* src = w1e + (size_t)(k0 + kk) * H_ + (h0 + bn);
      *(ushort4*)&Bl[bn][kk] = make_ushort4(f2bf(src[0]), f2bf(src[H_]), f2bf(src[2 * H_]), f2bf(src[3 * H_]));
    }
    __syncthreads();
    bf16x8 af[4], bfr[4];
#pragma unroll
    for (int i = 0; i < 4; ++i) af[i]  = *(const bf16x8*)&Al[wm + i * 16 + c16][kq];
#pragma unroll
    for (int i = 0; i < 4; ++i) bfr[i] = *(const bf16x8*)&Bl[wn + i * 16 + c16][kq];
#pragma unroll
    for (int mi = 0; mi < 4; ++mi)
#pragma unroll
      for (int ni = 0; ni < 4; ++ni)
        acc[mi][ni] = __builtin_amdgcn_mfma_f32_16x16x32_bf16(af[mi], bfr[ni], acc[mi][ni], 0, 0, 0);
    __syncthreads();
  }
  const float* b1e = b1 + (size_t)e * H_;
  unsigned short* hs = hact + (size_t)s * L_ * H_;
#pragma unroll
  for (int ni = 0; ni < 4; ++ni) {
    int n = h0 + wn + ni * 16 + c16;
    float bias = b1e[n];
#pragma unroll
    for (int mi = 0; mi < 4; ++mi)
#pragma unroll
      for (int j = 0; j < 4; ++j) {
        int m = l0 + wm + mi * 16 + rq + j;
        hs[(size_t)m * H_ + n] = f2bf(act_fn(acc[mi][ni][j] + bias, e) * g);
      }
  }
}

__global__ __launch_bounds__(256) void k_ffn2b(const unsigned short* __restrict__ hact,
                                               const float* __restrict__ w2,
                                               const float* __restrict__ b2,
                                               const int* __restrict__ slot_e,
                                               const float* __restrict__ slot_g,
                                               const float* __restrict__ x,
                                               float* __restrict__ y) {
  __shared__ unsigned short Al[128][40];
  __shared__ unsigned short Bl[128][40];
  const int b = blockIdx.z;
  const int l0 = blockIdx.y * 128, d0 = blockIdx.x * 128;
  const int t = threadIdx.x, lane = t & 63, w = t >> 6;
  const int wm = (w >> 1) * 64, wn = (w & 1) * 64;
  const int c16 = lane & 15, kq = (lane >> 4) * 8, rq = (lane >> 4) * 4;
  const int ar = t >> 3, ac = (t & 7) * 4;
  const int bn = t & 127, bk0 = (t >> 7) * 4;
  f32x4 acc[4][4] = {};
  for (int si = 0; si < 2; ++si) {
    const int s = 2 * b + si;
    const int e = slot_e[s];
    const unsigned short* hs = hact + (size_t)s * L_ * H_;
    const float* w2e = w2 + (size_t)e * H_ * D_;
    for (int k0 = 0; k0 < H_; k0 += 32) {
#pragma unroll
      for (int p = 0; p < 4; ++p) {
        int r = p * 32 + ar;
        *(ushort4*)&Al[r][ac] = *(const ushort4*)(hs + (size_t)(l0 + r) * H_ + (k0 + ac));
      }
#pragma unroll
      for (int p = 0; p < 4; ++p) {
        int kk = bk0 + p * 8;
        const float* src = w2e + (size_t)(k0 + kk) * D_ + (d0 + bn);
        *(ushort4*)&Bl[bn][kk] = make_ushort4(f2bf(src[0]), f2bf(src[D_]), f2bf(src[2 * D_]), f2bf(src[3 * D_]));
      }
      __syncthreads();
      bf16x8 af[4], bfr[4];
#pragma unroll
      for (int i = 0; i < 4; ++i) af[i]  = *(const bf16x8*)&Al[wm + i * 16 + c16][kq];
#pragma unroll
      for (int i = 0; i < 4; ++i) bfr[i] = *(const bf16x8*)&Bl[wn + i * 16 + c16][kq];
#pragma unroll
      for (int mi = 0; mi < 4; ++mi)
#pragma unroll
        for (int ni = 0; ni < 4; ++ni)
          acc[mi][ni] = __builtin_amdgcn_mfma_f32_16x16x32_bf16(af[mi], bfr[ni], acc[mi][ni], 0, 0, 0);
      __syncthreads();
    }
  }
  const int e0 = slot_e[2 * b], e1 = slot_e[2 * b + 1];
  const float g0 = slot_g[2 * b], g1 = slot_g[2 * b + 1];
  const float* xb = x + (size_t)b * L_ * D_;
  float* yb = y + (size_t)b * L_ * D_;
#pragma unroll
  for (int ni = 0; ni < 4; ++ni) {
    int n = d0 + wn + ni * 16 + c16;
    float bias = g0 * b2[e0 * D_ + n] + g1 * b2[e1 * D_ + n];
#pragma unroll
    for (int mi = 0; mi < 4; ++mi)
#pragma unroll
      for (int j = 0; j < 4; ++j) {
        int m = l0 + wm + mi * 16 + rq + j;
        yb[(size_t)m * D_ + n] = acc[mi][ni][j] + bias + xb[(size_t)m * D_ + n];
      }
  }
}

__global__ __launch_bounds__(256) void k_ln_b(float* __restrict__ y,
                                              const float* __restrict__ g,
                                              const float* __restrict__ bt) {
  const int t = threadIdx.x;
  const int row = blockIdx.x * 4 + (t >> 6);
  const int lane = t & 63;
  float* yr = y + (size_t)row * D_;
  float4 v[3];
  float sum = 0.f;
#pragma unroll
  for (int i = 0; i < 3; ++i) {
    v[i] = *(const float4*)(yr + i * 256 + lane * 4);
    sum += v[i].x + v[i].y + v[i].z + v[i].w;
  }
#pragma unroll
  for (int off = 32; off > 0; off >>= 1) sum += __shfl_xor(sum, off);
  const float mu = sum * (1.0f / D_);
  float var = 0.f;
#pragma unroll
  for (int i = 0; i < 3; ++i) {
    v[i].x -= mu; v[i].y -= mu; v[i].z -= mu; v[i].w -= mu;
    var += v[i].x * v[i].x + v[i].y * v[i].y + v[i].z * v[i].z + v[i].w * v[i].w;
  }
#pragma unroll
  for (int off = 32; off > 0; off >>= 1) var += __shfl_xor(var, off);
  const float rstd = rsqrtf(var * (1.0f / D_) + 1e-5f);
#pragma unroll
  for (int i = 0; i < 3; ++i) {
    float4 gg = *(const float4*)(g + i * 256 + lane * 4);
    float4 bb = *(const float4*)(bt + i * 256 + lane * 4);
    float4 o;
    o.x = v[i].x * rstd * gg.x + bb.x;
    o.y = v[i].y * rstd * gg.y + bb.y;
    o.z = v[i].z * rstd * gg.z + bb.z;
    o.w = v[i].w * rstd * gg.w + bb.w;
    *(float4*)(yr + i * 256 + lane * 4) = o;
  }
}

extern "C" void kernel_launch(void* const* d_in, const int* in_sizes, int n_in,
                              void* d_out, int out_size, void* d_ws, size_t ws_size,
                              hipStream_t stream) {
  const float* x  = (const float*)d_in[0];
  const float* rw = (const float*)d_in[1];
  const float* rb = (const float*)d_in[2];
  const float* w1 = (const float*)d_in[3];
  const float* b1 = (const float*)d_in[4];
  const float* w2 = (const float*)d_in[5];
  const float* b2 = (const float*)d_in[6];
  const float* lg = (const float*)d_in[7];
  const float* lb = (const float*)d_in[8];
  float* y = (float*)d_out;

  char* ws = (char*)d_ws;
  int*   slot_e = (int*)ws;
  float* slot_g = (float*)(ws + 64);
  float* part   = (float*)(ws + 256);

  const size_t OFF_XBF  = 524288ull;
  const size_t OFF_WBUF = OFF_XBF + 12582912ull;   // 8*1024*768 bf16
  const size_t OFF_HACT = OFF_WBUF + 9437184ull;   // 4*768*1536 bf16 (shared w1t/w2t)
  const size_t NEED_A   = OFF_HACT + 50331648ull;  // 16*1024*1536 bf16  => 69.5 MB

  if (ws_size >= NEED_A) {
    unsigned short* xbf   = (unsigned short*)(ws + OFF_XBF);
    unsigned short* wbuf  = (unsigned short*)(ws + OFF_WBUF);
    unsigned short* hact  = (unsigned short*)(ws + OFF_HACT);
    unsigned short* ypart = (unsigned short*)(ws + OFF_XBF);  // aliases xbf (dead after ffn1)

    k_cvtx_pool<<<dim3(16, 8), 192, 0, stream>>>(x, xbf, part);
    k_route    <<<8,           256, 0, stream>>>(part, rw, rb, slot_e, slot_g);
    k_cvtw     <<<dim3(48, 24, 4), 256, 0, stream>>>(w1, wbuf, D_, H_);   // [D][H]->[H][D]
    k_ffn1a    <<<1536, 256, 0, stream>>>(xbf, wbuf, b1, slot_e, slot_g, hact);
    k_cvtw     <<<dim3(24, 48, 4), 256, 0, stream>>>(w2, wbuf, H_, D_);   // [H][D]->[D][H]
    k_ffn2a    <<<768,  256, 0, stream>>>(hact, wbuf, b2, slot_e, slot_g, x, y, ypart);
    k_ln       <<<2048, 256, 0, stream>>>(y, ypart, lg, lb);
  } else {
    unsigned short* hact = (unsigned short*)(ws + (1 << 19));
    k_cvtx_pool<<<dim3(16, 8), 192, 0, stream>>>(x, nullptr, part);
    k_route    <<<8,           256, 0, stream>>>(part, rw, rb, slot_e, slot_g);
    k_ffn1b    <<<dim3(12, 8, 16), 256, 0, stream>>>(x, w1, b1, slot_e, slot_g, hact);
    k_ffn2b    <<<dim3(6, 8, 8),   256, 0, stream>>>(hact, w2, b2, slot_e, slot_g, x, y);
    k_ln_b     <<<2048,        256, 0, stream>>>(y, lg, lb);
  }
}

// Round 9
// 151.221 us; speedup vs baseline: 1.1595x; 1.1595x over previous
//
#include <hip/hip_runtime.h>

#define B_ 8
#define L_ 1024
#define D_ 768
#define E_ 4
#define H_ 1536

typedef __attribute__((ext_vector_type(8))) short bf16x8;
typedef __attribute__((ext_vector_type(4))) float f32x4;

#define AS1 __attribute__((address_space(1)))
#define AS3 __attribute__((address_space(3)))

__device__ __forceinline__ unsigned short f2bf(float f) {
  unsigned int u = __float_as_uint(f);
  u += 0x7FFFu + ((u >> 16) & 1u);
  return (unsigned short)(u >> 16);
}
__device__ __forceinline__ float bf2f(unsigned short h) {
  return __uint_as_float(((unsigned int)h) << 16);
}

// ---- branch-free fast activations (hw exp2/rcp) ----
__device__ __forceinline__ float sigm(float z) {            // 1/(1+e^-z)
  return __builtin_amdgcn_rcpf(1.0f + __builtin_amdgcn_exp2f(z * -1.442695040888963f));
}
__device__ __forceinline__ float act_fn(float v, int e) {
  if (e == 1) return v * sigm(v);                           // silu
  if (e == 2) {                                             // mish = v*tanh(softplus(v))
    float p = __builtin_amdgcn_exp2f(fminf(v, 30.0f) * 1.442695040888963f);
    float q = 1.0f + p, q2 = q * q;                         // tanh(ln q) = (q^2-1)/(q^2+1)
    return v * (q2 - 1.0f) * __builtin_amdgcn_rcpf(q2 + 1.0f);
  }
  float u = v * (0.7978845608028654f + 0.0356774081f * v * v);  // gelu = v*sigma(2u)
  return v * sigm(2.0f * u);
}

// ---------- fused pre-kernel: cvtx_pool U cvtw(w1) U cvtw(w2, optional) ----------
__device__ __forceinline__ void cvtw_body(const float* __restrict__ src,
                                          unsigned short* __restrict__ dst,
                                          int R, int C, int bx, int by, int e,
                                          float (*tile)[33]) {
  const float* s = src + (size_t)e * R * C;
  unsigned short* d = dst + (size_t)e * R * C;
  const int c0 = bx * 32, r0 = by * 32;
  const int tx = threadIdx.x & 31, ty = threadIdx.x >> 5;
#pragma unroll
  for (int i = 0; i < 32; i += 8)
    tile[ty + i][tx] = s[(size_t)(r0 + ty + i) * C + c0 + tx];
  __syncthreads();
  const int c = threadIdx.x >> 3, r4 = (threadIdx.x & 7) * 4;
  ushort4 o = make_ushort4(f2bf(tile[r4 + 0][c]), f2bf(tile[r4 + 1][c]),
                           f2bf(tile[r4 + 2][c]), f2bf(tile[r4 + 3][c]));
  *(ushort4*)&d[(size_t)(c0 + c) * R + r0 + r4] = o;
}

__global__ __launch_bounds__(256) void k_pre(const float* __restrict__ x,
                                             unsigned short* __restrict__ xbf,
                                             float* __restrict__ part,
                                             const float* __restrict__ w1,
                                             unsigned short* __restrict__ w1t,
                                             const float* __restrict__ w2,
                                             unsigned short* __restrict__ w2t) {
  __shared__ float tile[32][33];
  int bid = blockIdx.x;
  if (bid < 128) {                              // cvtx_pool: c = bid&15, b = bid>>4
    const int t = threadIdx.x;
    if (t >= 192) return;
    const int c = bid & 15, b = bid >> 4;
    const float* xb = x + ((size_t)b * L_ + (size_t)c * 64) * D_;
    unsigned short* ob = xbf + ((size_t)b * L_ + (size_t)c * 64) * D_;
    float4 s = make_float4(0.f, 0.f, 0.f, 0.f);
    for (int l = 0; l < 64; ++l) {
      float4 v = *(const float4*)(xb + (size_t)l * D_ + t * 4);
      s.x += v.x; s.y += v.y; s.z += v.z; s.w += v.w;
      *(ushort4*)(ob + (size_t)l * D_ + t * 4) =
          make_ushort4(f2bf(v.x), f2bf(v.y), f2bf(v.z), f2bf(v.w));
    }
    *(float4*)(part + ((size_t)b * 16 + c) * D_ + t * 4) = s;
    return;
  }
  bid -= 128;
  if (bid < 4608) {                             // w1 [D][H] -> [H][D]
    cvtw_body(w1, w1t, D_, H_, bid % 48, (bid / 48) % 24, bid / 1152, tile);
    return;
  }
  bid -= 4608;                                  // w2 [H][D] -> [D][H] (only if staged early)
  cvtw_body(w2, w2t, H_, D_, bid % 24, (bid / 24) % 48, bid / 1152, tile);
}

// ---------- standalone cvtw (w2 conversion between GEMMs in shared-buffer mode) ----------
__global__ __launch_bounds__(256) void k_cvtw(const float* __restrict__ src,
                                              unsigned short* __restrict__ dst,
                                              int R, int C) {
  __shared__ float tile[32][33];
  cvtw_body(src, dst, R, C, blockIdx.x, blockIdx.y, blockIdx.z, tile);
}

// ---------- per-block routing (bit-identical to old k_route) ----------
__device__ __forceinline__ void route_block(const float* __restrict__ part,
                                            const float* __restrict__ rw,
                                            const float* __restrict__ rb,
                                            int s, float* red, int t,
                                            int& e_out, float& g_out) {
  const int b = s >> 1, si = s & 1;
  float p0 = 0.f, p1 = 0.f, p2 = 0.f;
  const float* pb = part + (size_t)b * 16 * D_;
  for (int c = 0; c < 16; ++c) {
    p0 += pb[c * D_ + t];
    p1 += pb[c * D_ + t + 256];
    p2 += pb[c * D_ + t + 512];
  }
  p0 *= (1.0f / L_); p1 *= (1.0f / L_); p2 *= (1.0f / L_);
  for (int e = 0; e < 4; ++e)
    red[t * 4 + e] = p0 * rw[e * D_ + t] + p1 * rw[e * D_ + t + 256] + p2 * rw[e * D_ + t + 512];
  __syncthreads();
  for (int ss = 128; ss > 0; ss >>= 1) {
    if (t < ss)
      for (int e = 0; e < 4; ++e) red[t * 4 + e] += red[(t + ss) * 4 + e];
    __syncthreads();
  }
  float lg[4];
  for (int e = 0; e < 4; ++e) lg[e] = red[e] + rb[e];
  int i0 = 0;
  for (int e = 1; e < 4; ++e) if (lg[e] > lg[i0]) i0 = e;
  int i1 = -1;
  for (int e = 0; e < 4; ++e) {
    if (e == i0) continue;
    if (i1 < 0 || lg[e] > lg[i1]) i1 = e;
  }
  float ex = expf(lg[i1] - lg[i0]);
  if (si == 0) { e_out = i0; g_out = 1.0f / (1.0f + ex); }
  else         { e_out = i1; g_out = ex / (1.0f + ex); }
  __syncthreads();   // routing LDS reads done before staging overwrites smem
}

// ---------- standalone route (fallback mode only) ----------
__global__ __launch_bounds__(256) void k_route(const float* __restrict__ part,
                                               const float* __restrict__ rw,
                                               const float* __restrict__ rb,
                                               int* __restrict__ slot_e,
                                               float* __restrict__ slot_g) {
  __shared__ float red[256 * 4];
  int e0, e1; float g0, g1;
  route_block(part, rw, rb, 2 * (int)blockIdx.x,     red, threadIdx.x, e0, g0);
  route_block(part, rw, rb, 2 * (int)blockIdx.x + 1, red, threadIdx.x, e1, g1);
  if (threadIdx.x == 0) {
    slot_e[2 * blockIdx.x] = e0;     slot_g[2 * blockIdx.x] = g0;
    slot_e[2 * blockIdx.x + 1] = e1; slot_g[2 * blockIdx.x + 1] = g1;
  }
}

// ---------- swizzled global_load_lds staging of a 128x32 bf16 tile (8 KB) ----------
// bank-group (4*row + slot) % 8 is a permutation over rows 0..7 -> 2-way aliasing (free).
// Both-sides swizzle: linear LDS dest, pre-swizzled global source, swizzled read.
__device__ __forceinline__ void stage_tile(const unsigned short* __restrict__ src, int pitch,
                                           unsigned short* lds, int t) {
#pragma unroll
  for (int rnd = 0; rnd < 2; ++rnd) {
    const int o = rnd * 4096 + t * 16;                     // dest byte offset
    const int row = o >> 6;
    const int kb = (o & 63) ^ (((row >> 1) & 3) << 4);     // swizzled source byte-in-row
    const unsigned short* g = src + (size_t)row * pitch + (kb >> 1);
    unsigned short* d = lds + ((o & ~1023) >> 1);          // wave-uniform base
    __builtin_amdgcn_global_load_lds((AS1 const void*)g, (AS3 void*)d, 16, 0, 0);
  }
}

__device__ __forceinline__ bf16x8 frag(const unsigned short* lds, int row, int kq8) {
  const int byte = (row << 6) + ((kq8 << 1) ^ (((row >> 1) & 3) << 4));
  return *(const bf16x8*)((const char*)lds + byte);
}

__device__ __forceinline__ void block_bar() {
  asm volatile("" ::: "memory");
  __builtin_amdgcn_s_barrier();
  asm volatile("" ::: "memory");
}

// ---------- K3a: GEMM1, depth-3 ring + counted vmcnt; fused routing prologue ----------
__global__ __launch_bounds__(256) void k_ffn1a(const unsigned short* __restrict__ xbf,
                                               const unsigned short* __restrict__ w1t,
                                               const float* __restrict__ b1,
                                               const float* __restrict__ part,
                                               const float* __restrict__ rw,
                                               const float* __restrict__ rb,
                                               unsigned short* __restrict__ hact) {
  __shared__ char smem[49152];
  unsigned short (*Abuf)[4096] = (unsigned short(*)[4096])smem;            // 24 KB
  unsigned short (*Bbuf)[4096] = (unsigned short(*)[4096])(smem + 24576);  // 24 KB
  // chunked XCD swizzle: 1536 blocks, 192/XCD
  int wg = blockIdx.x;
  wg = (wg & 7) * 192 + (wg >> 3);
  const int hx = wg % 12;
  const int ly = (wg / 12) & 7;
  const int s  = wg / 96;
  const int t = threadIdx.x, lane = t & 63, w = t >> 6;
  int e; float g;
  route_block(part, rw, rb, s, (float*)smem, t, e, g);
  const int b = s >> 1;
  const int l0 = ly * 128, h0 = hx * 128;
  const int wm = (w >> 1) * 64, wn = (w & 1) * 64;
  const int c16 = lane & 15, kq8 = (lane >> 4) * 8, rq = (lane >> 4) * 4;
  const unsigned short* A  = xbf + ((size_t)b * L_ + l0) * D_;
  const unsigned short* Bp = w1t + ((size_t)e * H_ + h0) * D_;
  f32x4 acc[4][4] = {};
  const int NT = D_ / 32;   // 24

  stage_tile(A,      D_, Abuf[0], t); stage_tile(Bp,      D_, Bbuf[0], t);
  stage_tile(A + 32, D_, Abuf[1], t); stage_tile(Bp + 32, D_, Bbuf[1], t);
  stage_tile(A + 64, D_, Abuf[2], t); stage_tile(Bp + 64, D_, Bbuf[2], t);
  int cb = 0;
  for (int kt = 0; kt < NT; ++kt) {
    if (kt + 3 <= NT)      asm volatile("s_waitcnt vmcnt(8)" ::: "memory");
    else if (kt + 2 == NT) asm volatile("s_waitcnt vmcnt(4)" ::: "memory");
    else                   asm volatile("s_waitcnt vmcnt(0)" ::: "memory");
    block_bar();
    const unsigned short* Ac = Abuf[cb];
    const unsigned short* Bc = Bbuf[cb];
    bf16x8 af[4], bfr[4];
#pragma unroll
    for (int i = 0; i < 4; ++i) af[i]  = frag(Ac, wm + i * 16 + c16, kq8);
#pragma unroll
    for (int i = 0; i < 4; ++i) bfr[i] = frag(Bc, wn + i * 16 + c16, kq8);
#pragma unroll
    for (int mi = 0; mi < 4; ++mi)
#pragma unroll
      for (int ni = 0; ni < 4; ++ni)
        acc[mi][ni] = __builtin_amdgcn_mfma_f32_16x16x32_bf16(af[mi], bfr[ni], acc[mi][ni], 0, 0, 0);
    block_bar();
    if (kt + 3 < NT) {
      stage_tile(A + (kt + 3) * 32,  D_, Abuf[cb], t);
      stage_tile(Bp + (kt + 3) * 32, D_, Bbuf[cb], t);
    }
    cb = (cb == 2) ? 0 : cb + 1;
  }

  // epilogue: act -> bf16 -> LDS tile [128][136] -> 16B coalesced stores (256B runs)
  const float* b1e = b1 + (size_t)e * H_;
  unsigned short* Cl = (unsigned short*)smem;
#pragma unroll
  for (int ni = 0; ni < 4; ++ni) {
    int n = wn + ni * 16 + c16;
    float bias = b1e[h0 + n];
#pragma unroll
    for (int mi = 0; mi < 4; ++mi)
#pragma unroll
      for (int j = 0; j < 4; ++j) {
        int m = wm + mi * 16 + rq + j;
        Cl[m * 136 + n] = f2bf(act_fn(acc[mi][ni][j] + bias, e) * g);
      }
  }
  __syncthreads();
  unsigned short* hs = hact + (((size_t)s * L_ + l0) * H_) + h0;
  const int rr = t >> 4, cc8 = (t & 15) * 8;
#pragma unroll
  for (int i = 0; i < 8; ++i) {
    int r = i * 16 + rr;
    *(bf16x8*)(hs + (size_t)r * H_ + cc8) = *(const bf16x8*)(Cl + r * 136 + cc8);
  }
}

// ---------- K4a: GEMM2; si=0 -> y f32(+resid), si=1 -> ypart via LDS bounce ----------
__global__ __launch_bounds__(256) void k_ffn2a(const unsigned short* __restrict__ hact,
                                               const unsigned short* __restrict__ w2t,
                                               const float* __restrict__ b2,
                                               const float* __restrict__ part,
                                               const float* __restrict__ rw,
                                               const float* __restrict__ rb,
                                               const float* __restrict__ x,
                                               float* __restrict__ y,
                                               unsigned short* __restrict__ ypart) {
  __shared__ char smem[49152];
  unsigned short (*Abuf)[4096] = (unsigned short(*)[4096])smem;
  unsigned short (*Bbuf)[4096] = (unsigned short(*)[4096])(smem + 24576);
  // chunked XCD swizzle: 768 blocks, 96/XCD
  int wg = blockIdx.x;
  wg = (wg & 7) * 96 + (wg >> 3);
  const int dx = wg % 6;
  const int ly = (wg / 6) & 7;
  const int s  = wg / 48;
  const int t = threadIdx.x, lane = t & 63, w = t >> 6;
  int e; float g;
  route_block(part, rw, rb, s, (float*)smem, t, e, g);
  const int si = s & 1, b = s >> 1;
  const int l0 = ly * 128, d0 = dx * 128;
  const int wm = (w >> 1) * 64, wn = (w & 1) * 64;
  const int c16 = lane & 15, kq8 = (lane >> 4) * 8, rq = (lane >> 4) * 4;
  const unsigned short* A  = hact + ((size_t)s * L_ + l0) * H_;
  const unsigned short* Bp = w2t + ((size_t)e * D_ + d0) * H_;
  f32x4 acc[4][4] = {};
  const int NT = H_ / 32;   // 48

  stage_tile(A,      H_, Abuf[0], t); stage_tile(Bp,      H_, Bbuf[0], t);
  stage_tile(A + 32, H_, Abuf[1], t); stage_tile(Bp + 32, H_, Bbuf[1], t);
  stage_tile(A + 64, H_, Abuf[2], t); stage_tile(Bp + 64, H_, Bbuf[2], t);
  int cb = 0;
  for (int kt = 0; kt < NT; ++kt) {
    if (kt + 3 <= NT)      asm volatile("s_waitcnt vmcnt(8)" ::: "memory");
    else if (kt + 2 == NT) asm volatile("s_waitcnt vmcnt(4)" ::: "memory");
    else                   asm volatile("s_waitcnt vmcnt(0)" ::: "memory");
    block_bar();
    const unsigned short* Ac = Abuf[cb];
    const unsigned short* Bc = Bbuf[cb];
    bf16x8 af[4], bfr[4];
#pragma unroll
    for (int i = 0; i < 4; ++i) af[i]  = frag(Ac, wm + i * 16 + c16, kq8);
#pragma unroll
    for (int i = 0; i < 4; ++i) bfr[i] = frag(Bc, wn + i * 16 + c16, kq8);
#pragma unroll
    for (int mi = 0; mi < 4; ++mi)
#pragma unroll
      for (int ni = 0; ni < 4; ++ni)
        acc[mi][ni] = __builtin_amdgcn_mfma_f32_16x16x32_bf16(af[mi], bfr[ni], acc[mi][ni], 0, 0, 0);
    block_bar();
    if (kt + 3 < NT) {
      stage_tile(A + (kt + 3) * 32,  H_, Abuf[cb], t);
      stage_tile(Bp + (kt + 3) * 32, H_, Bbuf[cb], t);
    }
    cb = (cb == 2) ? 0 : cb + 1;
  }

  if (si == 0) {
    const float* xb = x + (size_t)b * L_ * D_;
    float* yb = y + (size_t)b * L_ * D_;
#pragma unroll
    for (int ni = 0; ni < 4; ++ni) {
      int n = d0 + wn + ni * 16 + c16;
      float bias = g * b2[(size_t)e * D_ + n];
#pragma unroll
      for (int mi = 0; mi < 4; ++mi)
#pragma unroll
        for (int j = 0; j < 4; ++j) {
          int m = l0 + wm + mi * 16 + rq + j;
          yb[(size_t)m * D_ + n] = acc[mi][ni][j] + bias + xb[(size_t)m * D_ + n];
        }
    }
  } else {
    unsigned short* Cl = (unsigned short*)smem;
#pragma unroll
    for (int ni = 0; ni < 4; ++ni) {
      int n = wn + ni * 16 + c16;
      float bias = g * b2[(size_t)e * D_ + d0 + n];
#pragma unroll
      for (int mi = 0; mi < 4; ++mi)
#pragma unroll
        for (int j = 0; j < 4; ++j) {
          int m = wm + mi * 16 + rq + j;
          Cl[m * 136 + n] = f2bf(acc[mi][ni][j] + bias);
        }
    }
    __syncthreads();
    unsigned short* yp = ypart + ((size_t)b * L_ + l0) * D_ + d0;
    const int rr = t >> 4, cc8 = (t & 15) * 8;
#pragma unroll
    for (int i = 0; i < 8; ++i) {
      int r = i * 16 + rr;
      *(bf16x8*)(yp + (size_t)r * D_ + cc8) = *(const bf16x8*)(Cl + r * 136 + cc8);
    }
  }
}

// ---------- K5: row LayerNorm, 1 wave per row, shuffle reductions, no LDS ----------
__global__ __launch_bounds__(256) void k_ln(float* __restrict__ y,
                                            const unsigned short* __restrict__ yp,
                                            const float* __restrict__ g,
                                            const float* __restrict__ bt) {
  const int t = threadIdx.x;
  const int row = blockIdx.x * 4 + (t >> 6);
  const int lane = t & 63;
  float* yr = y + (size_t)row * D_;
  float4 v[3];
  float sum = 0.f;
#pragma unroll
  for (int i = 0; i < 3; ++i) {
    v[i] = *(const float4*)(yr + i * 256 + lane * 4);
    if (yp) {
      ushort4 p = *(const ushort4*)(yp + (size_t)row * D_ + i * 256 + lane * 4);
      v[i].x += bf2f(p.x); v[i].y += bf2f(p.y); v[i].z += bf2f(p.z); v[i].w += bf2f(p.w);
    }
    sum += v[i].x + v[i].y + v[i].z + v[i].w;
  }
#pragma unroll
  for (int off = 32; off > 0; off >>= 1) sum += __shfl_xor(sum, off);
  const float mu = sum * (1.0f / D_);
  float var = 0.f;
#pragma unroll
  for (int i = 0; i < 3; ++i) {
    v[i].x -= mu; v[i].y -= mu; v[i].z -= mu; v[i].w -= mu;
    var += v[i].x * v[i].x + v[i].y * v[i].y + v[i].z * v[i].z + v[i].w * v[i].w;
  }
#pragma unroll
  for (int off = 32; off > 0; off >>= 1) var += __shfl_xor(var, off);
  const float rstd = rsqrtf(var * (1.0f / D_) + 1e-5f);
#pragma unroll
  for (int i = 0; i < 3; ++i) {
    float4 gg = *(const float4*)(g + i * 256 + lane * 4);
    float4 bb = *(const float4*)(bt + i * 256 + lane * 4);
    float4 o;
    o.x = v[i].x * rstd * gg.x + bb.x;
    o.y = v[i].y * rstd * gg.y + bb.y;
    o.z = v[i].z * rstd * gg.z + bb.z;
    o.w = v[i].w * rstd * gg.w + bb.w;
    *(float4*)(yr + i * 256 + lane * 4) = o;
  }
}

// ================= fallback (mode B, round-1 proven kernels) =================
__global__ __launch_bounds__(192) void k_poolb(const float* __restrict__ x,
                                               float* __restrict__ part) {
  const int c = blockIdx.x, b = blockIdx.y, t = threadIdx.x;
  const float* xb = x + ((size_t)b * L_ + (size_t)c * 64) * D_;
  float4 s = make_float4(0.f, 0.f, 0.f, 0.f);
  for (int l = 0; l < 64; ++l) {
    float4 v = *(const float4*)(xb + (size_t)l * D_ + t * 4);
    s.x += v.x; s.y += v.y; s.z += v.z; s.w += v.w;
  }
  *(float4*)(part + ((size_t)b * 16 + c) * D_ + t * 4) = s;
}

__global__ __launch_bounds__(256) void k_ffn1b(const float* __restrict__ x,
                                               const float* __restrict__ w1,
                                               const float* __restrict__ b1,
                                               const int* __restrict__ slot_e,
                                               const float* __restrict__ slot_g,
                                               unsigned short* __restrict__ hact) {
  __shared__ unsigned short Al[128][40];
  __shared__ unsigned short Bl[128][40];
  const int s = blockIdx.z;
  const int e = slot_e[s];
  const float g = slot_g[s];
  const int b = s >> 1;
  const int l0 = blockIdx.y * 128, h0 = blockIdx.x * 128;
  const int t = threadIdx.x, lane = t & 63, w = t >> 6;
  const int wm = (w >> 1) * 64, wn = (w & 1) * 64;
  const int c16 = lane & 15, kq = (lane >> 4) * 8, rq = (lane >> 4) * 4;
  const int ar = t >> 3, ac = (t & 7) * 4;
  const int bn = t & 127, bk0 = (t >> 7) * 4;
  const float* xb  = x  + (size_t)b * L_ * D_;
  const float* w1e = w1 + (size_t)e * D_ * H_;
  f32x4 acc[4][4] = {};
  for (int k0 = 0; k0 < D_; k0 += 32) {
#pragma unroll
    for (int p = 0; p < 4; ++p) {
      int r = p * 32 + ar;
      float4 v = *(const float4*)(xb + (size_t)(l0 + r) * D_ + (k0 + ac));
      *(ushort4*)&Al[r][ac] = make_ushort4(f2bf(v.x), f2bf(v.y), f2bf(v.z), f2bf(v.w));
    }
#pragma unroll
    for (int p = 0; p < 4; ++p) {
      int kk = bk0 + p * 8;
      const float* src = w1e + (size_t)(k0 + kk) * H_ + (h0 + bn);
      *(ushort4*)&Bl[bn][kk] = make_ushort4(f2bf(src[0]), f2bf(src[H_]), f2bf(src[2 * H_]), f2bf(src[3 * H_]));
    }
    __syncthreads();
    bf16x8 af[4], bfr[4];
#pragma unroll
    for (int i = 0; i < 4; ++i) af[i]  = *(const bf16x8*)&Al[wm + i * 16 + c16][kq];
#pragma unroll
    for (int i = 0; i < 4; ++i) bfr[i] = *(const bf16x8*)&Bl[wn + i * 16 + c16][kq];
#pragma unroll
    for (int mi = 0; mi < 4; ++mi)
#pragma unroll
      for (int ni = 0; ni < 4; ++ni)
        acc[mi][ni] = __builtin_amdgcn_mfma_f32_16x16x32_bf16(af[mi], bfr[ni], acc[mi][ni], 0, 0, 0);
    __syncthreads();
  }
  const float* b1e = b1 + (size_t)e * H_;
  unsigned short* hs = hact + (size_t)s * L_ * H_;
#pragma unroll
  for (int ni = 0; ni < 4; ++ni) {
    int n = h0 + wn + ni * 16 + c16;
    float bias = b1e[n];
#pragma unroll
    for (int mi = 0; mi < 4; ++mi)
#pragma unroll
      for (int j = 0; j < 4; ++j) {
        int m = l0 + wm + mi * 16 + rq + j;
        hs[(size_t)m * H_ + n] = f2bf(act_fn(acc[mi][ni][j] + bias, e) * g);
      }
  }
}

__global__ __launch_bounds__(256) void k_ffn2b(const unsigned short* __restrict__ hact,
                                               const float* __restrict__ w2,
                                               const float* __restrict__ b2,
                                               const int* __restrict__ slot_e,
                                               const float* __restrict__ slot_g,
                                               const float* __restrict__ x,
                                               float* __restrict__ y) {
  __shared__ unsigned short Al[128][40];
  __shared__ unsigned short Bl[128][40];
  const int b = blockIdx.z;
  const int l0 = blockIdx.y * 128, d0 = blockIdx.x * 128;
  const int t = threadIdx.x, lane = t & 63, w = t >> 6;
  const int wm = (w >> 1) * 64, wn = (w & 1) * 64;
  const int c16 = lane & 15, kq = (lane >> 4) * 8, rq = (lane >> 4) * 4;
  const int ar = t >> 3, ac = (t & 7) * 4;
  const int bn = t & 127, bk0 = (t >> 7) * 4;
  f32x4 acc[4][4] = {};
  for (int si = 0; si < 2; ++si) {
    const int s = 2 * b + si;
    const int e = slot_e[s];
    const unsigned short* hs = hact + (size_t)s * L_ * H_;
    const float* w2e = w2 + (size_t)e * H_ * D_;
    for (int k0 = 0; k0 < H_; k0 += 32) {
#pragma unroll
      for (int p = 0; p < 4; ++p) {
        int r = p * 32 + ar;
        *(ushort4*)&Al[r][ac] = *(const ushort4*)(hs + (size_t)(l0 + r) * H_ + (k0 + ac));
      }
#pragma unroll
      for (int p = 0; p < 4; ++p) {
        int kk = bk0 + p * 8;
        const float* src = w2e + (size_t)(k0 + kk) * D_ + (d0 + bn);
        *(ushort4*)&Bl[bn][kk] = make_ushort4(f2bf(src[0]), f2bf(src[D_]), f2bf(src[2 * D_]), f2bf(src[3 * D_]));
      }
      __syncthreads();
      bf16x8 af[4], bfr[4];
#pragma unroll
      for (int i = 0; i < 4; ++i) af[i]  = *(const bf16x8*)&Al[wm + i * 16 + c16][kq];
#pragma unroll
      for (int i = 0; i < 4; ++i) bfr[i] = *(const bf16x8*)&Bl[wn + i * 16 + c16][kq];
#pragma unroll
      for (int mi = 0; mi < 4; ++mi)
#pragma unroll
        for (int ni = 0; ni < 4; ++ni)
          acc[mi][ni] = __builtin_amdgcn_mfma_f32_16x16x32_bf16(af[mi], bfr[ni], acc[mi][ni], 0, 0, 0);
      __syncthreads();
    }
  }
  const int e0 = slot_e[2 * b], e1 = slot_e[2 * b + 1];
  const float g0 = slot_g[2 * b], g1 = slot_g[2 * b + 1];
  const float* xb = x + (size_t)b * L_ * D_;
  float* yb = y + (size_t)b * L_ * D_;
#pragma unroll
  for (int ni = 0; ni < 4; ++ni) {
    int n = d0 + wn + ni * 16 + c16;
    float bias = g0 * b2[e0 * D_ + n] + g1 * b2[e1 * D_ + n];
#pragma unroll
    for (int mi = 0; mi < 4; ++mi)
#pragma unroll
      for (int j = 0; j < 4; ++j) {
        int m = l0 + wm + mi * 16 + rq + j;
        yb[(size_t)m * D_ + n] = acc[mi][ni][j] + bias + xb[(size_t)m * D_ + n];
      }
  }
}

extern "C" void kernel_launch(void* const* d_in, const int* in_sizes, int n_in,
                              void* d_out, int out_size, void* d_ws, size_t ws_size,
                              hipStream_t stream) {
  const float* x  = (const float*)d_in[0];
  const float* rw = (const float*)d_in[1];
  const float* rb = (const float*)d_in[2];
  const float* w1 = (const float*)d_in[3];
  const float* b1 = (const float*)d_in[4];
  const float* w2 = (const float*)d_in[5];
  const float* b2 = (const float*)d_in[6];
  const float* lg = (const float*)d_in[7];
  const float* lb = (const float*)d_in[8];
  float* y = (float*)d_out;

  char* ws = (char*)d_ws;
  int*   slot_e = (int*)ws;
  float* slot_g = (float*)(ws + 64);
  float* part   = (float*)(ws + 256);

  const size_t OFF_XBF  = 524288ull;
  const size_t OFF_WBUF = OFF_XBF + 12582912ull;   // 8*1024*768 bf16
  const size_t OFF_HACT = OFF_WBUF + 9437184ull;   // 4*768*1536 bf16 (w1t; or shared w1t/w2t)
  const size_t NEED_A   = OFF_HACT + 50331648ull;  // + hact 16*1024*1536 bf16 => 69.5 MB
  const size_t OFF_W2T  = NEED_A;
  const size_t NEED_A2  = NEED_A + 9437184ull;     // + dedicated w2t => 78.5 MB

  if (ws_size >= NEED_A) {
    unsigned short* xbf   = (unsigned short*)(ws + OFF_XBF);
    unsigned short* wbuf  = (unsigned short*)(ws + OFF_WBUF);
    unsigned short* hact  = (unsigned short*)(ws + OFF_HACT);
    unsigned short* ypart = (unsigned short*)(ws + OFF_XBF);  // aliases xbf (dead after ffn1)

    if (ws_size >= NEED_A2) {
      unsigned short* w2t = (unsigned short*)(ws + OFF_W2T);
      k_pre  <<<128 + 4608 + 4608, 256, 0, stream>>>(x, xbf, part, w1, wbuf, w2, w2t);
      k_ffn1a<<<1536, 256, 0, stream>>>(xbf, wbuf, b1, part, rw, rb, hact);
      k_ffn2a<<<768,  256, 0, stream>>>(hact, w2t, b2, part, rw, rb, x, y, ypart);
      k_ln   <<<2048, 256, 0, stream>>>(y, ypart, lg, lb);
    } else {
      k_pre  <<<128 + 4608, 256, 0, stream>>>(x, xbf, part, w1, wbuf, w2, nullptr);
      k_ffn1a<<<1536, 256, 0, stream>>>(xbf, wbuf, b1, part, rw, rb, hact);
      k_cvtw <<<dim3(24, 48, 4), 256, 0, stream>>>(w2, wbuf, H_, D_);   // [H][D]->[D][H]
      k_ffn2a<<<768,  256, 0, stream>>>(hact, wbuf, b2, part, rw, rb, x, y, ypart);
      k_ln   <<<2048, 256, 0, stream>>>(y, ypart, lg, lb);
    }
  } else {
    unsigned short* hact = (unsigned short*)(ws + (1 << 19));
    k_poolb<<<dim3(16, 8), 192, 0, stream>>>(x, part);
    k_route<<<8,           256, 0, stream>>>(part, rw, rb, slot_e, slot_g);
    k_ffn1b<<<dim3(12, 8, 16), 256, 0, stream>>>(x, w1, b1, slot_e, slot_g, hact);
    k_ffn2b<<<dim3(6, 8, 8),   256, 0, stream>>>(hact, w2, b2, slot_e, slot_g, x, y);
    k_ln   <<<2048,        256, 0, stream>>>(y, nullptr, lg, lb);
  }
}

// Round 11
// 147.198 us; speedup vs baseline: 1.1912x; 1.0273x over previous
//
#include <hip/hip_runtime.h>

#define B_ 8
#define L_ 1024
#define D_ 768
#define E_ 4
#define H_ 1536

typedef __attribute__((ext_vector_type(8))) short bf16x8;
typedef __attribute__((ext_vector_type(4))) float f32x4;

#define AS1 __attribute__((address_space(1)))
#define AS3 __attribute__((address_space(3)))

__device__ __forceinline__ unsigned short f2bf(float f) {
  unsigned int u = __float_as_uint(f);
  u += 0x7FFFu + ((u >> 16) & 1u);
  return (unsigned short)(u >> 16);
}
__device__ __forceinline__ float bf2f(unsigned short h) {
  return __uint_as_float(((unsigned int)h) << 16);
}

// ---- branch-free fast activations (hw exp2/rcp) ----
__device__ __forceinline__ float sigm(float z) {            // 1/(1+e^-z)
  return __builtin_amdgcn_rcpf(1.0f + __builtin_amdgcn_exp2f(z * -1.442695040888963f));
}
__device__ __forceinline__ float act_fn(float v, int e) {
  if (e == 1) return v * sigm(v);                           // silu
  if (e == 2) {                                             // mish = v*tanh(softplus(v))
    float p = __builtin_amdgcn_exp2f(fminf(v, 30.0f) * 1.442695040888963f);
    float q = 1.0f + p, q2 = q * q;                         // tanh(ln q) = (q^2-1)/(q^2+1)
    return v * (q2 - 1.0f) * __builtin_amdgcn_rcpf(q2 + 1.0f);
  }
  float u = v * (0.7978845608028654f + 0.0356774081f * v * v);  // gelu = v*sigma(2u)
  return v * sigm(2.0f * u);
}

// ---------- fused pre-kernel: cvtx_pool U cvtw(w1) U cvtw(w2, optional) ----------
__device__ __forceinline__ void cvtw_body(const float* __restrict__ src,
                                          unsigned short* __restrict__ dst,
                                          int R, int C, int bx, int by, int e,
                                          float (*tile)[33]) {
  const float* s = src + (size_t)e * R * C;
  unsigned short* d = dst + (size_t)e * R * C;
  const int c0 = bx * 32, r0 = by * 32;
  const int tx = threadIdx.x & 31, ty = threadIdx.x >> 5;
#pragma unroll
  for (int i = 0; i < 32; i += 8)
    tile[ty + i][tx] = s[(size_t)(r0 + ty + i) * C + c0 + tx];
  __syncthreads();
  const int c = threadIdx.x >> 3, r4 = (threadIdx.x & 7) * 4;
  ushort4 o = make_ushort4(f2bf(tile[r4 + 0][c]), f2bf(tile[r4 + 1][c]),
                           f2bf(tile[r4 + 2][c]), f2bf(tile[r4 + 3][c]));
  *(ushort4*)&d[(size_t)(c0 + c) * R + r0 + r4] = o;
}

__global__ __launch_bounds__(256) void k_pre(const float* __restrict__ x,
                                             unsigned short* __restrict__ xbf,
                                             float* __restrict__ part,
                                             const float* __restrict__ w1,
                                             unsigned short* __restrict__ w1t,
                                             const float* __restrict__ w2,
                                             unsigned short* __restrict__ w2t) {
  __shared__ float tile[32][33];
  int bid = blockIdx.x;
  if (bid < 128) {                              // cvtx_pool: c = bid&15, b = bid>>4
    const int t = threadIdx.x;
    if (t >= 192) return;
    const int c = bid & 15, b = bid >> 4;
    const float* xb = x + ((size_t)b * L_ + (size_t)c * 64) * D_;
    unsigned short* ob = xbf + ((size_t)b * L_ + (size_t)c * 64) * D_;
    float4 s = make_float4(0.f, 0.f, 0.f, 0.f);
    for (int l = 0; l < 64; ++l) {
      float4 v = *(const float4*)(xb + (size_t)l * D_ + t * 4);
      s.x += v.x; s.y += v.y; s.z += v.z; s.w += v.w;
      *(ushort4*)(ob + (size_t)l * D_ + t * 4) =
          make_ushort4(f2bf(v.x), f2bf(v.y), f2bf(v.z), f2bf(v.w));
    }
    *(float4*)(part + ((size_t)b * 16 + c) * D_ + t * 4) = s;
    return;
  }
  bid -= 128;
  if (bid < 4608) {                             // w1 [D][H] -> [H][D]
    cvtw_body(w1, w1t, D_, H_, bid % 48, (bid / 48) % 24, bid / 1152, tile);
    return;
  }
  bid -= 4608;                                  // w2 [H][D] -> [D][H] (only if staged early)
  cvtw_body(w2, w2t, H_, D_, bid % 24, (bid / 24) % 48, bid / 1152, tile);
}

// ---------- standalone cvtw (w2 conversion between GEMMs in shared-buffer mode) ----------
__global__ __launch_bounds__(256) void k_cvtw(const float* __restrict__ src,
                                              unsigned short* __restrict__ dst,
                                              int R, int C) {
  __shared__ float tile[32][33];
  cvtw_body(src, dst, R, C, blockIdx.x, blockIdx.y, blockIdx.z, tile);
}

// ---------- routing: one block per sample, both slots ----------
__device__ __forceinline__ void route_block(const float* __restrict__ part,
                                            const float* __restrict__ rw,
                                            const float* __restrict__ rb,
                                            int b, float* red, int t,
                                            int* e01, float* g01) {
  float p0 = 0.f, p1 = 0.f, p2 = 0.f;
  const float* pb = part + (size_t)b * 16 * D_;
  for (int c = 0; c < 16; ++c) {
    p0 += pb[c * D_ + t];
    p1 += pb[c * D_ + t + 256];
    p2 += pb[c * D_ + t + 512];
  }
  p0 *= (1.0f / L_); p1 *= (1.0f / L_); p2 *= (1.0f / L_);
  for (int e = 0; e < 4; ++e)
    red[t * 4 + e] = p0 * rw[e * D_ + t] + p1 * rw[e * D_ + t + 256] + p2 * rw[e * D_ + t + 512];
  __syncthreads();
  for (int ss = 128; ss > 0; ss >>= 1) {
    if (t < ss)
      for (int e = 0; e < 4; ++e) red[t * 4 + e] += red[(t + ss) * 4 + e];
    __syncthreads();
  }
  float lg[4];
  for (int e = 0; e < 4; ++e) lg[e] = red[e] + rb[e];
  int i0 = 0;
  for (int e = 1; e < 4; ++e) if (lg[e] > lg[i0]) i0 = e;
  int i1 = -1;
  for (int e = 0; e < 4; ++e) {
    if (e == i0) continue;
    if (i1 < 0 || lg[e] > lg[i1]) i1 = e;
  }
  float ex = expf(lg[i1] - lg[i0]);
  e01[0] = i0; g01[0] = 1.0f / (1.0f + ex);
  e01[1] = i1; g01[1] = ex / (1.0f + ex);
}

__global__ __launch_bounds__(256) void k_route(const float* __restrict__ part,
                                               const float* __restrict__ rw,
                                               const float* __restrict__ rb,
                                               int* __restrict__ slot_e,
                                               float* __restrict__ slot_g) {
  __shared__ float red[256 * 4];
  int e01[2]; float g01[2];
  route_block(part, rw, rb, blockIdx.x, red, threadIdx.x, e01, g01);
  if (threadIdx.x == 0) {
    slot_e[2 * blockIdx.x]     = e01[0]; slot_g[2 * blockIdx.x]     = g01[0];
    slot_e[2 * blockIdx.x + 1] = e01[1]; slot_g[2 * blockIdx.x + 1] = g01[1];
  }
}

// ---------- swizzled global_load_lds staging of a 128x32 bf16 tile (8 KB) ----------
// bank-group (4*row + slot) % 8 is a permutation over rows 0..7 -> 2-way aliasing (free).
// Both-sides swizzle: linear LDS dest, pre-swizzled global source, swizzled read.
__device__ __forceinline__ void stage_tile(const unsigned short* __restrict__ src, int pitch,
                                           unsigned short* lds, int t) {
#pragma unroll
  for (int rnd = 0; rnd < 2; ++rnd) {
    const int o = rnd * 4096 + t * 16;                     // dest byte offset
    const int row = o >> 6;
    const int kb = (o & 63) ^ (((row >> 1) & 3) << 4);     // swizzled source byte-in-row
    const unsigned short* g = src + (size_t)row * pitch + (kb >> 1);
    unsigned short* d = lds + ((o & ~1023) >> 1);          // wave-uniform base
    __builtin_amdgcn_global_load_lds((AS1 const void*)g, (AS3 void*)d, 16, 0, 0);
  }
}

__device__ __forceinline__ bf16x8 frag(const unsigned short* lds, int row, int kq8) {
  const int byte = (row << 6) + ((kq8 << 1) ^ (((row >> 1) & 3) << 4));
  return *(const bf16x8*)((const char*)lds + byte);
}

__device__ __forceinline__ void block_bar() {
  asm volatile("" ::: "memory");
  __builtin_amdgcn_s_barrier();
  asm volatile("" ::: "memory");
}

// ---------- K3a: GEMM1, depth-3 ring + counted vmcnt; LDS-bounce coalesced epilogue ----
__global__ __launch_bounds__(256) void k_ffn1a(const unsigned short* __restrict__ xbf,
                                               const unsigned short* __restrict__ w1t,
                                               const float* __restrict__ b1,
                                               const int* __restrict__ slot_e,
                                               const float* __restrict__ slot_g,
                                               unsigned short* __restrict__ hact) {
  __shared__ char smem[49152];
  unsigned short (*Abuf)[4096] = (unsigned short(*)[4096])smem;            // 24 KB
  unsigned short (*Bbuf)[4096] = (unsigned short(*)[4096])(smem + 24576);  // 24 KB
  // chunked XCD swizzle: 1536 blocks, 192/XCD
  int wg = blockIdx.x;
  wg = (wg & 7) * 192 + (wg >> 3);
  const int hx = wg % 12;
  const int ly = (wg / 12) & 7;
  const int s  = wg / 96;
  const int e = slot_e[s];
  const float g = slot_g[s];
  const int b = s >> 1;
  const int l0 = ly * 128, h0 = hx * 128;
  const int t = threadIdx.x, lane = t & 63, w = t >> 6;
  const int wm = (w >> 1) * 64, wn = (w & 1) * 64;
  const int c16 = lane & 15, kq8 = (lane >> 4) * 8, rq = (lane >> 4) * 4;
  const unsigned short* A  = xbf + ((size_t)b * L_ + l0) * D_;
  const unsigned short* Bp = w1t + ((size_t)e * H_ + h0) * D_;
  f32x4 acc[4][4] = {};
  const int NT = D_ / 32;   // 24

  stage_tile(A,      D_, Abuf[0], t); stage_tile(Bp,      D_, Bbuf[0], t);
  stage_tile(A + 32, D_, Abuf[1], t); stage_tile(Bp + 32, D_, Bbuf[1], t);
  stage_tile(A + 64, D_, Abuf[2], t); stage_tile(Bp + 64, D_, Bbuf[2], t);
  int cb = 0;
  for (int kt = 0; kt < NT; ++kt) {
    if (kt + 3 <= NT)      asm volatile("s_waitcnt vmcnt(8)" ::: "memory");
    else if (kt + 2 == NT) asm volatile("s_waitcnt vmcnt(4)" ::: "memory");
    else                   asm volatile("s_waitcnt vmcnt(0)" ::: "memory");
    block_bar();
    const unsigned short* Ac = Abuf[cb];
    const unsigned short* Bc = Bbuf[cb];
    bf16x8 af[4], bfr[4];
#pragma unroll
    for (int i = 0; i < 4; ++i) af[i]  = frag(Ac, wm + i * 16 + c16, kq8);
#pragma unroll
    for (int i = 0; i < 4; ++i) bfr[i] = frag(Bc, wn + i * 16 + c16, kq8);
#pragma unroll
    for (int mi = 0; mi < 4; ++mi)
#pragma unroll
      for (int ni = 0; ni < 4; ++ni)
        acc[mi][ni] = __builtin_amdgcn_mfma_f32_16x16x32_bf16(af[mi], bfr[ni], acc[mi][ni], 0, 0, 0);
    asm volatile("s_waitcnt lgkmcnt(0)" ::: "memory");   // all LDS reads of buf[cb] retired
    block_bar();
    if (kt + 3 < NT) {
      stage_tile(A + (kt + 3) * 32,  D_, Abuf[cb], t);
      stage_tile(Bp + (kt + 3) * 32, D_, Bbuf[cb], t);
    }
    cb = (cb == 2) ? 0 : cb + 1;
  }

  // epilogue: act -> bf16 -> LDS tile [128][136] -> 16B coalesced stores (256B runs)
  const float* b1e = b1 + (size_t)e * H_;
  unsigned short* Cl = (unsigned short*)smem;
#pragma unroll
  for (int ni = 0; ni < 4; ++ni) {
    int n = wn + ni * 16 + c16;
    float bias = b1e[h0 + n];
#pragma unroll
    for (int mi = 0; mi < 4; ++mi)
#pragma unroll
      for (int j = 0; j < 4; ++j) {
        int m = wm + mi * 16 + rq + j;
        Cl[m * 136 + n] = f2bf(act_fn(acc[mi][ni][j] + bias, e) * g);
      }
  }
  __syncthreads();
  unsigned short* hs = hact + (((size_t)s * L_ + l0) * H_) + h0;
  const int rr = t >> 4, cc8 = (t & 15) * 8;
#pragma unroll
  for (int i = 0; i < 8; ++i) {
    int r = i * 16 + rr;
    *(bf16x8*)(hs + (size_t)r * H_ + cc8) = *(const bf16x8*)(Cl + r * 136 + cc8);
  }
}

// ---------- K4a: GEMM2; si=0 -> y f32(+resid, 64B runs), si=1 -> ypart via LDS bounce ----
__global__ __launch_bounds__(256) void k_ffn2a(const unsigned short* __restrict__ hact,
                                               const unsigned short* __restrict__ w2t,
                                               const float* __restrict__ b2,
                                               const int* __restrict__ slot_e,
                                               const float* __restrict__ slot_g,
                                               const float* __restrict__ x,
                                               float* __restrict__ y,
                                               unsigned short* __restrict__ ypart) {
  __shared__ char smem[49152];
  unsigned short (*Abuf)[4096] = (unsigned short(*)[4096])smem;
  unsigned short (*Bbuf)[4096] = (unsigned short(*)[4096])(smem + 24576);
  // chunked XCD swizzle: 768 blocks, 96/XCD
  int wg = blockIdx.x;
  wg = (wg & 7) * 96 + (wg >> 3);
  const int dx = wg % 6;
  const int ly = (wg / 6) & 7;
  const int s  = wg / 48;
  const int si = s & 1, b = s >> 1;
  const int e = slot_e[s];
  const float g = slot_g[s];
  const int l0 = ly * 128, d0 = dx * 128;
  const int t = threadIdx.x, lane = t & 63, w = t >> 6;
  const int wm = (w >> 1) * 64, wn = (w & 1) * 64;
  const int c16 = lane & 15, kq8 = (lane >> 4) * 8, rq = (lane >> 4) * 4;
  const unsigned short* A  = hact + ((size_t)s * L_ + l0) * H_;
  const unsigned short* Bp = w2t + ((size_t)e * D_ + d0) * H_;
  f32x4 acc[4][4] = {};
  const int NT = H_ / 32;   // 48

  stage_tile(A,      H_, Abuf[0], t); stage_tile(Bp,      H_, Bbuf[0], t);
  stage_tile(A + 32, H_, Abuf[1], t); stage_tile(Bp + 32, H_, Bbuf[1], t);
  stage_tile(A + 64, H_, Abuf[2], t); stage_tile(Bp + 64, H_, Bbuf[2], t);
  int cb = 0;
  for (int kt = 0; kt < NT; ++kt) {
    if (kt + 3 <= NT)      asm volatile("s_waitcnt vmcnt(8)" ::: "memory");
    else if (kt + 2 == NT) asm volatile("s_waitcnt vmcnt(4)" ::: "memory");
    else                   asm volatile("s_waitcnt vmcnt(0)" ::: "memory");
    block_bar();
    const unsigned short* Ac = Abuf[cb];
    const unsigned short* Bc = Bbuf[cb];
    bf16x8 af[4], bfr[4];
#pragma unroll
    for (int i = 0; i < 4; ++i) af[i]  = frag(Ac, wm + i * 16 + c16, kq8);
#pragma unroll
    for (int i = 0; i < 4; ++i) bfr[i] = frag(Bc, wn + i * 16 + c16, kq8);
#pragma unroll
    for (int mi = 0; mi < 4; ++mi)
#pragma unroll
      for (int ni = 0; ni < 4; ++ni)
        acc[mi][ni] = __builtin_amdgcn_mfma_f32_16x16x32_bf16(af[mi], bfr[ni], acc[mi][ni], 0, 0, 0);
    asm volatile("s_waitcnt lgkmcnt(0)" ::: "memory");   // all LDS reads of buf[cb] retired
    block_bar();
    if (kt + 3 < NT) {
      stage_tile(A + (kt + 3) * 32,  H_, Abuf[cb], t);
      stage_tile(Bp + (kt + 3) * 32, H_, Bbuf[cb], t);
    }
    cb = (cb == 2) ? 0 : cb + 1;
  }

  if (si == 0) {
    const float* xb = x + (size_t)b * L_ * D_;
    float* yb = y + (size_t)b * L_ * D_;
#pragma unroll
    for (int ni = 0; ni < 4; ++ni) {
      int n = d0 + wn + ni * 16 + c16;
      float bias = g * b2[(size_t)e * D_ + n];
#pragma unroll
      for (int mi = 0; mi < 4; ++mi)
#pragma unroll
        for (int j = 0; j < 4; ++j) {
          int m = l0 + wm + mi * 16 + rq + j;
          yb[(size_t)m * D_ + n] = acc[mi][ni][j] + bias + xb[(size_t)m * D_ + n];
        }
    }
  } else {
    unsigned short* Cl = (unsigned short*)smem;
#pragma unroll
    for (int ni = 0; ni < 4; ++ni) {
      int n = wn + ni * 16 + c16;
      float bias = g * b2[(size_t)e * D_ + d0 + n];
#pragma unroll
      for (int mi = 0; mi < 4; ++mi)
#pragma unroll
        for (int j = 0; j < 4; ++j) {
          int m = wm + mi * 16 + rq + j;
          Cl[m * 136 + n] = f2bf(acc[mi][ni][j] + bias);
        }
    }
    __syncthreads();
    unsigned short* yp = ypart + ((size_t)b * L_ + l0) * D_ + d0;
    const int rr = t >> 4, cc8 = (t & 15) * 8;
#pragma unroll
    for (int i = 0; i < 8; ++i) {
      int r = i * 16 + rr;
      *(bf16x8*)(yp + (size_t)r * D_ + cc8) = *(const bf16x8*)(Cl + r * 136 + cc8);
    }
  }
}

// ---------- K5: row LayerNorm, 1 wave per row, shuffle reductions, no LDS ----------
__global__ __launch_bounds__(256) void k_ln(float* __restrict__ y,
                                            const unsigned short* __restrict__ yp,
                                            const float* __restrict__ g,
                                            const float* __restrict__ bt) {
  const int t = threadIdx.x;
  const int row = blockIdx.x * 4 + (t >> 6);
  const int lane = t & 63;
  float* yr = y + (size_t)row * D_;
  float4 v[3];
  float sum = 0.f;
#pragma unroll
  for (int i = 0; i < 3; ++i) {
    v[i] = *(const float4*)(yr + i * 256 + lane * 4);
    if (yp) {
      ushort4 p = *(const ushort4*)(yp + (size_t)row * D_ + i * 256 + lane * 4);
      v[i].x += bf2f(p.x); v[i].y += bf2f(p.y); v[i].z += bf2f(p.z); v[i].w += bf2f(p.w);
    }
    sum += v[i].x + v[i].y + v[i].z + v[i].w;
  }
#pragma unroll
  for (int off = 32; off > 0; off >>= 1) sum += __shfl_xor(sum, off);
  const float mu = sum * (1.0f / D_);
  float var = 0.f;
#pragma unroll
  for (int i = 0; i < 3; ++i) {
    v[i].x -= mu; v[i].y -= mu; v[i].z -= mu; v[i].w -= mu;
    var += v[i].x * v[i].x + v[i].y * v[i].y + v[i].z * v[i].z + v[i].w * v[i].w;
  }
#pragma unroll
  for (int off = 32; off > 0; off >>= 1) var += __shfl_xor(var, off);
  const float rstd = rsqrtf(var * (1.0f / D_) + 1e-5f);
#pragma unroll
  for (int i = 0; i < 3; ++i) {
    float4 gg = *(const float4*)(g + i * 256 + lane * 4);
    float4 bb = *(const float4*)(bt + i * 256 + lane * 4);
    float4 o;
    o.x = v[i].x * rstd * gg.x + bb.x;
    o.y = v[i].y * rstd * gg.y + bb.y;
    o.z = v[i].z * rstd * gg.z + bb.z;
    o.w = v[i].w * rstd * gg.w + bb.w;
    *(float4*)(yr + i * 256 + lane * 4) = o;
  }
}

// ================= fallback (mode B, round-1 proven kernels) =================
__global__ __launch_bounds__(192) void k_poolb(const float* __restrict__ x,
                                               float* __restrict__ part) {
  const int c = blockIdx.x, b = blockIdx.y, t = threadIdx.x;
  const float* xb = x + ((size_t)b * L_ + (size_t)c * 64) * D_;
  float4 s = make_float4(0.f, 0.f, 0.f, 0.f);
  for (int l = 0; l < 64; ++l) {
    float4 v = *(const float4*)(xb + (size_t)l * D_ + t * 4);
    s.x += v.x; s.y += v.y; s.z += v.z; s.w += v.w;
  }
  *(float4*)(part + ((size_t)b * 16 + c) * D_ + t * 4) = s;
}

__global__ __launch_bounds__(256) void k_ffn1b(const float* __restrict__ x,
                                               const float* __restrict__ w1,
                                               const float* __restrict__ b1,
                                               const int* __restrict__ slot_e,
                                               const float* __restrict__ slot_g,
                                               unsigned short* __restrict__ hact) {
  __shared__ unsigned short Al[128][40];
  __shared__ unsigned short Bl[128][40];
  const int s = blockIdx.z;
  const int e = slot_e[s];
  const float g = slot_g[s];
  const int b = s >> 1;
  const int l0 = blockIdx.y * 128, h0 = blockIdx.x * 128;
  const int t = threadIdx.x, lane = t & 63, w = t >> 6;
  const int wm = (w >> 1) * 64, wn = (w & 1) * 64;
  const int c16 = lane & 15, kq = (lane >> 4) * 8, rq = (lane >> 4) * 4;
  const int ar = t >> 3, ac = (t & 7) * 4;
  const int bn = t & 127, bk0 = (t >> 7) * 4;
  const float* xb  = x  + (size_t)b * L_ * D_;
  const float* w1e = w1 + (size_t)e * D_ * H_;
  f32x4 acc[4][4] = {};
  for (int k0 = 0; k0 < D_; k0 += 32) {
#pragma unroll
    for (int p = 0; p < 4; ++p) {
      int r = p * 32 + ar;
      float4 v = *(const float4*)(xb + (size_t)(l0 + r) * D_ + (k0 + ac));
      *(ushort4*)&Al[r][ac] = make_ushort4(f2bf(v.x), f2bf(v.y), f2bf(v.z), f2bf(v.w));
    }
#pragma unroll
    for (int p = 0; p < 4; ++p) {
      int kk = bk0 + p * 8;
      const float* src = w1e + (size_t)(k0 + kk) * H_ + (h0 + bn);
      *(ushort4*)&Bl[bn][kk] = make_ushort4(f2bf(src[0]), f2bf(src[H_]), f2bf(src[2 * H_]), f2bf(src[3 * H_]));
    }
    __syncthreads();
    bf16x8 af[4], bfr[4];
#pragma unroll
    for (int i = 0; i < 4; ++i) af[i]  = *(const bf16x8*)&Al[wm + i * 16 + c16][kq];
#pragma unroll
    for (int i = 0; i < 4; ++i) bfr[i] = *(const bf16x8*)&Bl[wn + i * 16 + c16][kq];
#pragma unroll
    for (int mi = 0; mi < 4; ++mi)
#pragma unroll
      for (int ni = 0; ni < 4; ++ni)
        acc[mi][ni] = __builtin_amdgcn_mfma_f32_16x16x32_bf16(af[mi], bfr[ni], acc[mi][ni], 0, 0, 0);
    __syncthreads();
  }
  const float* b1e = b1 + (size_t)e * H_;
  unsigned short* hs = hact + (size_t)s * L_ * H_;
#pragma unroll
  for (int ni = 0; ni < 4; ++ni) {
    int n = h0 + wn + ni * 16 + c16;
    float bias = b1e[n];
#pragma unroll
    for (int mi = 0; mi < 4; ++mi)
#pragma unroll
      for (int j = 0; j < 4; ++j) {
        int m = l0 + wm + mi * 16 + rq + j;
        hs[(size_t)m * H_ + n] = f2bf(act_fn(acc[mi][ni][j] + bias, e) * g);
      }
  }
}

__global__ __launch_bounds__(256) void k_ffn2b(const unsigned short* __restrict__ hact,
                                               const float* __restrict__ w2,
                                               const float* __restrict__ b2,
                                               const int* __restrict__ slot_e,
                                               const float* __restrict__ slot_g,
                                               const float* __restrict__ x,
                                               float* __restrict__ y) {
  __shared__ unsigned short Al[128][40];
  __shared__ unsigned short Bl[128][40];
  const int b = blockIdx.z;
  const int l0 = blockIdx.y * 128, d0 = blockIdx.x * 128;
  const int t = threadIdx.x, lane = t & 63, w = t >> 6;
  const int wm = (w >> 1) * 64, wn = (w & 1) * 64;
  const int c16 = lane & 15, kq = (lane >> 4) * 8, rq = (lane >> 4) * 4;
  const int ar = t >> 3, ac = (t & 7) * 4;
  const int bn = t & 127, bk0 = (t >> 7) * 4;
  f32x4 acc[4][4] = {};
  for (int si = 0; si < 2; ++si) {
    const int s = 2 * b + si;
    const int e = slot_e[s];
    const unsigned short* hs = hact + (size_t)s * L_ * H_;
    const float* w2e = w2 + (size_t)e * H_ * D_;
    for (int k0 = 0; k0 < H_; k0 += 32) {
#pragma unroll
      for (int p = 0; p < 4; ++p) {
        int r = p * 32 + ar;
        *(ushort4*)&Al[r][ac] = *(const ushort4*)(hs + (size_t)(l0 + r) * H_ + (k0 + ac));
      }
#pragma unroll
      for (int p = 0; p < 4; ++p) {
        int kk = bk0 + p * 8;
        const float* src = w2e + (size_t)(k0 + kk) * D_ + (d0 + bn);
        *(ushort4*)&Bl[bn][kk] = make_ushort4(f2bf(src[0]), f2bf(src[D_]), f2bf(src[2 * D_]), f2bf(src[3 * D_]));
      }
      __syncthreads();
      bf16x8 af[4], bfr[4];
#pragma unroll
      for (int i = 0; i < 4; ++i) af[i]  = *(const bf16x8*)&Al[wm + i * 16 + c16][kq];
#pragma unroll
      for (int i = 0; i < 4; ++i) bfr[i] = *(const bf16x8*)&Bl[wn + i * 16 + c16][kq];
#pragma unroll
      for (int mi = 0; mi < 4; ++mi)
#pragma unroll
        for (int ni = 0; ni < 4; ++ni)
          acc[mi][ni] = __builtin_amdgcn_mfma_f32_16x16x32_bf16(af[mi], bfr[ni], acc[mi][ni], 0, 0, 0);
      __syncthreads();
    }
  }
  const int e0 = slot_e[2 * b], e1 = slot_e[2 * b + 1];
  const float g0 = slot_g[2 * b], g1 = slot_g[2 * b + 1];
  const float* xb = x + (size_t)b * L_ * D_;
  float* yb = y + (size_t)b * L_ * D_;
#pragma unroll
  for (int ni = 0; ni < 4; ++ni) {
    int n = d0 + wn + ni * 16 + c16;
    float bias = g0 * b2[e0 * D_ + n] + g1 * b2[e1 * D_ + n];
#pragma unroll
    for (int mi = 0; mi < 4; ++mi)
#pragma unroll
      for (int j = 0; j < 4; ++j) {
        int m = l0 + wm + mi * 16 + rq + j;
        yb[(size_t)m * D_ + n] = acc[mi][ni][j] + bias + xb[(size_t)m * D_ + n];
      }
  }
}

extern "C" void kernel_launch(void* const* d_in, const int* in_sizes, int n_in,
                              void* d_out, int out_size, void* d_ws, size_t ws_size,
                              hipStream_t stream) {
  const float* x  = (const float*)d_in[0];
  const float* rw = (const float*)d_in[1];
  const float* rb = (const float*)d_in[2];
  const float* w1 = (const float*)d_in[3];
  const float* b1 = (const float*)d_in[4];
  const float* w2 = (const float*)d_in[5];
  const float* b2 = (const float*)d_in[6];
  const float* lg = (const float*)d_in[7];
  const float* lb = (const float*)d_in[8];
  float* y = (float*)d_out;

  char* ws = (char*)d_ws;
  int*   slot_e = (int*)ws;
  float* slot_g = (float*)(ws + 64);
  float* part   = (float*)(ws + 256);

  const size_t OFF_XBF  = 524288ull;
  const size_t OFF_WBUF = OFF_XBF + 12582912ull;   // 8*1024*768 bf16
  const size_t OFF_HACT = OFF_WBUF + 9437184ull;   // 4*768*1536 bf16 (w1t; or shared w1t/w2t)
  const size_t NEED_A   = OFF_HACT + 50331648ull;  // + hact 16*1024*1536 bf16 => 69.5 MB
  const size_t OFF_W2T  = NEED_A;
  const size_t NEED_A2  = NEED_A + 9437184ull;     // + dedicated w2t => 78.5 MB

  if (ws_size >= NEED_A) {
    unsigned short* xbf   = (unsigned short*)(ws + OFF_XBF);
    unsigned short* wbuf  = (unsigned short*)(ws + OFF_WBUF);
    unsigned short* hact  = (unsigned short*)(ws + OFF_HACT);
    unsigned short* ypart = (unsigned short*)(ws + OFF_XBF);  // aliases xbf (dead after ffn1)

    if (ws_size >= NEED_A2) {
      unsigned short* w2t = (unsigned short*)(ws + OFF_W2T);
      k_pre  <<<128 + 4608 + 4608, 256, 0, stream>>>(x, xbf, part, w1, wbuf, w2, w2t);
      k_route<<<8, 256, 0, stream>>>(part, rw, rb, slot_e, slot_g);
      k_ffn1a<<<1536, 256, 0, stream>>>(xbf, wbuf, b1, slot_e, slot_g, hact);
      k_ffn2a<<<768,  256, 0, stream>>>(hact, w2t, b2, slot_e, slot_g, x, y, ypart);
      k_ln   <<<2048, 256, 0, stream>>>(y, ypart, lg, lb);
    } else {
      k_pre  <<<128 + 4608, 256, 0, stream>>>(x, xbf, part, w1, wbuf, w2, nullptr);
      k_route<<<8, 256, 0, stream>>>(part, rw, rb, slot_e, slot_g);
      k_ffn1a<<<1536, 256, 0, stream>>>(xbf, wbuf, b1, slot_e, slot_g, hact);
      k_cvtw <<<dim3(24, 48, 4), 256, 0, stream>>>(w2, wbuf, H_, D_);   // [H][D]->[D][H]
      k_ffn2a<<<768,  256, 0, stream>>>(hact, wbuf, b2, slot_e, slot_g, x, y, ypart);
      k_ln   <<<2048, 256, 0, stream>>>(y, ypart, lg, lb);
    }
  } else {
    unsigned short* hact = (unsigned short*)(ws + (1 << 19));
    k_poolb<<<dim3(16, 8), 192, 0, stream>>>(x, part);
    k_route<<<8,           256, 0, stream>>>(part, rw, rb, slot_e, slot_g);
    k_ffn1b<<<dim3(12, 8, 16), 256, 0, stream>>>(x, w1, b1, slot_e, slot_g, hact);
    k_ffn2b<<<dim3(6, 8, 8),   256, 0, stream>>>(hact, w2, b2, slot_e, slot_g, x, y);
    k_ln   <<<2048,        256, 0, stream>>>(y, nullptr, lg, lb);
  }
}